// Round 1
// baseline (24.484 us; speedup 1.0000x reference)
//
#include <hip/hip_runtime.h>
#include <math.h>

// Problem constants (from reference setup_inputs)
constexpr int NN  = 64;    // nodes per graph
constexpr int EE  = 256;   // edges per graph
constexpr int NH  = 64;    // hidden dim
constexpr int KK  = 32;    // SAGPool keep count

// One wave (64 threads) per graph. lane = node index, later feature index.
__global__ __launch_bounds__(64) void graph_feat_kernel(
    const int*   __restrict__ graph_edges,  // [G,2,E]
    const float* __restrict__ conv1_w,      // [64]
    const float* __restrict__ conv1_b,      // [64]
    const float* __restrict__ wrel,         // [64]
    const float* __restrict__ brel,         // [1]
    const float* __restrict__ wroot,        // [64]
    const float* __restrict__ pred_w,       // [256]
    float*       __restrict__ ab)           // [G,2]  a=feat.pw[0:128], b=feat.pw[128:256]
{
    const int g    = blockIdx.x;
    const int lane = threadIdx.x;  // 0..63

    __shared__ int   s_src[EE];
    __shared__ int   s_dst[EE];
    __shared__ float s_deg[NN];
    __shared__ float s_dinv[NN];
    __shared__ float s_acc[NN];    // sum of dinv[src] per dst, later c[n]
    __shared__ float s_t[NN];      // h[m] . wrel
    __shared__ float s_score[NN];
    __shared__ float s_tanh[NN];
    __shared__ int   s_keep[NN];
    __shared__ float s_w[NH], s_b[NH], s_wr[NH], s_wo[NH];

    // stage weights (broadcast-read later)
    s_w[lane]  = conv1_w[lane];
    s_b[lane]  = conv1_b[lane];
    s_wr[lane] = wrel[lane];
    s_wo[lane] = wroot[lane];

    // load edges: lane loads 4 src + 4 dst
    const int* eg = graph_edges + (size_t)g * 2 * EE;
    #pragma unroll
    for (int i = 0; i < 4; ++i) {
        s_src[lane + 64 * i] = eg[lane + 64 * i];
        s_dst[lane + 64 * i] = eg[EE + lane + 64 * i];
    }
    s_deg[lane] = 1.0f;  // self-loop contributes 1
    s_acc[lane] = 0.0f;
    __syncthreads();

    // in-degree via LDS atomics (exact: integer-valued fp32 adds)
    #pragma unroll
    for (int i = 0; i < 4; ++i)
        atomicAdd(&s_deg[s_dst[lane + 64 * i]], 1.0f);
    __syncthreads();

    const float deg  = s_deg[lane];
    const float dinv = 1.0f / sqrtf(deg);
    s_dinv[lane] = dinv;
    __syncthreads();

    // sumnorm numerator: sum over incoming edges of dinv[src]
    #pragma unroll
    for (int i = 0; i < 4; ++i) {
        const int e = lane + 64 * i;
        atomicAdd(&s_acc[s_dst[e]], s_dinv[s_src[e]]);
    }
    __syncthreads();

    // c[n]: h[n][j] = relu(w_j * c[n] + b_j)
    const float c = s_acc[lane] * dinv + 1.0f / deg;
    s_acc[lane] = c;

    // per-node scalars t = h.wrel, u = h.wroot
    float t = 0.0f, u = 0.0f;
    for (int j = 0; j < NH; ++j) {
        const float h = fmaxf(s_w[j] * c + s_b[j], 0.0f);
        t = fmaf(h, s_wr[j], t);
        u = fmaf(h, s_wo[j], u);
    }
    s_t[lane] = t;
    s_score[lane] = u + brel[0];
    __syncthreads();

    // score[n] += sum over incoming edges of t[src]
    #pragma unroll
    for (int i = 0; i < 4; ++i) {
        const int e = lane + 64 * i;
        atomicAdd(&s_score[s_dst[e]], s_t[s_src[e]]);
    }
    __syncthreads();

    // stable top-K by rank (JAX tie semantics: lower index wins on ties)
    const float score = s_score[lane];
    int rank = 0;
    for (int m = 0; m < NN; ++m) {
        const float sm = s_score[m];
        rank += (sm > score) || (sm == score && m < lane);
    }
    const int keep = (rank < KK) ? 1 : 0;
    s_keep[lane] = keep;
    s_tanh[lane] = keep ? tanhf(score) : 0.0f;
    __syncthreads();

    // lane is now feature index j: max/mean over kept nodes of h[n][j]*tanh(score[n])
    const float wj = s_w[lane], bj = s_b[lane];
    float fmx = -INFINITY, fsum = 0.0f;
    for (int n = 0; n < NN; ++n) {
        if (s_keep[n]) {  // wave-uniform branch
            const float h = fmaxf(wj * s_acc[n] + bj, 0.0f);
            const float v = h * s_tanh[n];
            fmx  = fmaxf(fmx, v);
            fsum += v;
        }
    }
    const float fmean = fsum * (1.0f / KK);

    // a = feat . pred_w[0:128], b = feat . pred_w[128:256] via wave reduction
    float pa = fmx * pred_w[lane]       + fmean * pred_w[64 + lane];
    float pb = fmx * pred_w[128 + lane] + fmean * pred_w[192 + lane];
    #pragma unroll
    for (int off = 32; off > 0; off >>= 1) {
        pa += __shfl_down(pa, off);
        pb += __shfl_down(pb, off);
    }
    if (lane == 0) {
        ab[2 * g]     = pa;
        ab[2 * g + 1] = pb;
    }
}

__global__ __launch_bounds__(256) void pred_kernel(
    const int*   __restrict__ ddi,   // [2,P]
    const float* __restrict__ ab,    // [G,2]
    const float* __restrict__ pred_b,
    float*       __restrict__ out,   // [P]
    int P)
{
    const int p = blockIdx.x * blockDim.x + threadIdx.x;
    if (p >= P) return;
    const int s = ddi[p];
    const int d = ddi[P + p];
    const float x = ab[2 * s] + ab[2 * d + 1] + pred_b[0];
    out[p] = 1.0f / (1.0f + __expf(-x) * 0.0f + expf(-x) * 1.0f);
}

extern "C" void kernel_launch(void* const* d_in, const int* in_sizes, int n_in,
                              void* d_out, int out_size, void* d_ws, size_t ws_size,
                              hipStream_t stream) {
    const int*   graph_edges = (const int*)  d_in[0];
    const int*   ddi         = (const int*)  d_in[1];
    const float* conv1_w     = (const float*)d_in[2];
    const float* conv1_b     = (const float*)d_in[3];
    const float* wrel        = (const float*)d_in[4];
    const float* brel        = (const float*)d_in[5];
    const float* wroot       = (const float*)d_in[6];
    const float* pred_w      = (const float*)d_in[7];
    const float* pred_b      = (const float*)d_in[8];
    float*       out         = (float*)d_out;

    const int G = in_sizes[0] / (2 * EE);   // 2048
    const int P = in_sizes[1] / 2;          // 200000

    float* ab = (float*)d_ws;               // [G,2]

    graph_feat_kernel<<<G, 64, 0, stream>>>(
        graph_edges, conv1_w, conv1_b, wrel, brel, wroot, pred_w, ab);

    pred_kernel<<<(P + 255) / 256, 256, 0, stream>>>(
        ddi, ab, pred_b, out, P);
}